// Round 1
// baseline (734.200 us; speedup 1.0000x reference)
//
#include <hip/hip_runtime.h>
#include <math.h>

#define NNODES 50000
#define NEDGES 800000
#define NTOT   (NNODES + NEDGES)

// ---------------- CSR build ----------------

__global__ __launch_bounds__(256) void hist_kernel(const int* __restrict__ ei,
                                                   int* __restrict__ counts) {
  int e = blockIdx.x * 256 + threadIdx.x;
  if (e >= NTOT) return;
  int dst = (e < NEDGES) ? ei[NEDGES + e] : (e - NEDGES);
  atomicAdd(&counts[dst], 1);
}

// single-block exclusive scan: counts[] -> indptr[] (and counts becomes cursor)
__global__ __launch_bounds__(1024) void scan_kernel(int* __restrict__ counts,
                                                    int* __restrict__ indptr) {
  __shared__ int wsum[16];
  __shared__ int wpre[16];
  __shared__ int tot_s;
  int t = threadIdx.x;
  int lane = t & 63, w = t >> 6;
  int base = 0;
  for (int start = 0; start < NNODES; start += 1024) {
    __syncthreads();
    int i = start + t;
    int v = (i < NNODES) ? counts[i] : 0;
    int x = v;
    #pragma unroll
    for (int off = 1; off < 64; off <<= 1) {
      int y = __shfl_up(x, off, 64);
      if (lane >= off) x += y;
    }
    if (lane == 63) wsum[w] = x;
    __syncthreads();
    if (t < 16) {
      int s = wsum[t];
      int xs = s;
      #pragma unroll
      for (int off = 1; off < 16; off <<= 1) {
        int y = __shfl_up(xs, off, 16);
        if (t >= off) xs += y;
      }
      wpre[t] = xs - s;
      if (t == 15) tot_s = xs;
    }
    __syncthreads();
    int excl = base + wpre[w] + (x - v);
    if (i < NNODES) { indptr[i] = excl; counts[i] = excl; }
    base += tot_s;
  }
  if (t == 0) indptr[NNODES] = base;
}

__global__ __launch_bounds__(256) void scatter_kernel(const int* __restrict__ ei,
                                                      int* __restrict__ cursor,
                                                      int* __restrict__ csrc) {
  int e = blockIdx.x * 256 + threadIdx.x;
  if (e >= NTOT) return;
  int src, dst;
  if (e < NEDGES) { src = ei[e]; dst = ei[NEDGES + e]; }
  else            { src = e - NEDGES; dst = src; }
  int pos = atomicAdd(&cursor[dst], 1);
  csrc[pos] = src;
}

// ---------------- GEMM h = X @ W  (+ fused alpha_src/dst = h . a) ----------------
// block: 256 threads, 32 rows x 128 cols, whole W in LDS, 4x4 micro-tile.

__global__ __launch_bounds__(256) void gemm_alpha_kernel(
    const float* __restrict__ X, const float* __restrict__ Wm,
    const float* __restrict__ a_src, const float* __restrict__ a_dst,
    float* __restrict__ H, float* __restrict__ alps, float* __restrict__ alpd) {
  __shared__ float wl[128 * 128];   // W [k][n], 64 KB
  __shared__ float xt[128][36];     // X tile transposed [k][r], padded
  int t = threadIdx.x;
  int r0 = blockIdx.x * 32;

  { // stage W (64KB): 4096 float4 / 256 threads = 16 each
    const float4* W4 = (const float4*)Wm;
    float4* wl4 = (float4*)wl;
    #pragma unroll
    for (int i = 0; i < 16; ++i) wl4[t + 256 * i] = W4[t + 256 * i];
  }
  { // stage X tile transposed: thread -> (r = t&31, k0 = (t>>5)*16)
    int r = t & 31;
    int k0 = (t >> 5) * 16;
    int row = r0 + r;
    if (row < NNODES) {
      const float4* xp = (const float4*)(X + (size_t)row * 128 + k0);
      #pragma unroll
      for (int q = 0; q < 4; ++q) {
        float4 vv = xp[q];
        int k = k0 + q * 4;
        xt[k + 0][r] = vv.x; xt[k + 1][r] = vv.y;
        xt[k + 2][r] = vv.z; xt[k + 3][r] = vv.w;
      }
    } else {
      #pragma unroll
      for (int q = 0; q < 16; ++q) xt[k0 + q][r] = 0.f;
    }
  }
  __syncthreads();

  int tc = t & 31;   // cols 4*tc .. 4*tc+3
  int tr = t >> 5;   // rows 4*tr .. 4*tr+3
  float acc[4][4];
  #pragma unroll
  for (int r = 0; r < 4; ++r)
    #pragma unroll
    for (int c = 0; c < 4; ++c) acc[r][c] = 0.f;

  #pragma unroll 4
  for (int k = 0; k < 128; ++k) {
    float4 wv = *(const float4*)(&wl[k * 128 + tc * 4]);
    float4 xv = *(const float4*)(&xt[k][tr * 4]);
    float xr[4] = {xv.x, xv.y, xv.z, xv.w};
    float wc[4] = {wv.x, wv.y, wv.z, wv.w};
    #pragma unroll
    for (int r = 0; r < 4; ++r)
      #pragma unroll
      for (int c = 0; c < 4; ++c) acc[r][c] = fmaf(xr[r], wc[c], acc[r][c]);
  }

  // epilogue: write H, reduce alpha partials across the 8 threads of each (row, head)
  int hd  = tc >> 3;          // head of this thread's 4 columns
  int cin = (tc & 7) * 4;     // col within head
  float as0 = a_src[hd * 32 + cin + 0], as1 = a_src[hd * 32 + cin + 1];
  float as2 = a_src[hd * 32 + cin + 2], as3 = a_src[hd * 32 + cin + 3];
  float ad0 = a_dst[hd * 32 + cin + 0], ad1 = a_dst[hd * 32 + cin + 1];
  float ad2 = a_dst[hd * 32 + cin + 2], ad3 = a_dst[hd * 32 + cin + 3];

  #pragma unroll
  for (int r = 0; r < 4; ++r) {
    int row = r0 + tr * 4 + r;
    float4 hv = make_float4(acc[r][0], acc[r][1], acc[r][2], acc[r][3]);
    float ps = hv.x * as0 + hv.y * as1 + hv.z * as2 + hv.w * as3;
    float pd = hv.x * ad0 + hv.y * ad1 + hv.z * ad2 + hv.w * ad3;
    #pragma unroll
    for (int off = 1; off < 8; off <<= 1) {  // 8 lanes share (row, head)
      ps += __shfl_xor(ps, off, 64);
      pd += __shfl_xor(pd, off, 64);
    }
    if (row < NNODES) {
      *(float4*)(&H[(size_t)row * 128 + tc * 4]) = hv;
      if ((tc & 7) == 0) {
        alps[row * 4 + hd] = ps;
        alpd[row * 4 + hd] = pd;
      }
    }
  }
}

// ---------------- aggregation: one wave per dst node, online softmax ----------------

__global__ __launch_bounds__(256) void agg_kernel(
    const float* __restrict__ H, const float* __restrict__ alps,
    const float* __restrict__ alpd, const int* __restrict__ indptr,
    const int* __restrict__ csrc, const float* __restrict__ bias,
    float* __restrict__ out, int relu_flag) {
  int wid = (blockIdx.x * 256 + threadIdx.x) >> 6;
  if (wid >= NNODES) return;
  int lane = threadIdx.x & 63;
  int hd  = lane >> 4;                 // head
  int col = hd * 32 + (lane & 15) * 2; // 2 channels per lane -> 128 per wave
  float adv = alpd[wid * 4 + hd];
  int beg = indptr[wid], end = indptr[wid + 1];

  float m = -INFINITY, s = 0.f, a0 = 0.f, a1 = 0.f;
  for (int j = beg; j < end; ++j) {
    int src = csrc[j];
    float av = alps[src * 4 + hd] + adv;
    float e  = (av > 0.f) ? av : 0.2f * av;   // leaky_relu 0.2
    float nm = fmaxf(m, e);
    float sc = __expf(m - nm);                // exp(-inf)=0 on first edge
    float p  = __expf(e - nm);
    const float2 hv = *(const float2*)(&H[(size_t)src * 128 + col]);
    s  = s  * sc + p;
    a0 = a0 * sc + p * hv.x;
    a1 = a1 * sc + p * hv.y;
    m = nm;
  }
  float inv = 1.0f / s;
  float o0 = a0 * inv + bias[col + 0];
  float o1 = a1 * inv + bias[col + 1];
  if (relu_flag) { o0 = fmaxf(o0, 0.f); o1 = fmaxf(o1, 0.f); }
  *(float2*)(&out[(size_t)wid * 128 + col]) = make_float2(o0, o1);
}

// ---------------- launch ----------------

extern "C" void kernel_launch(void* const* d_in, const int* in_sizes, int n_in,
                              void* d_out, int out_size, void* d_ws, size_t ws_size,
                              hipStream_t stream) {
  const float* x  = (const float*)d_in[0];
  const int*   ei = (const int*)d_in[1];
  const float* W[4]  = {(const float*)d_in[2],  (const float*)d_in[6],
                        (const float*)d_in[10], (const float*)d_in[14]};
  const float* As[4] = {(const float*)d_in[3],  (const float*)d_in[7],
                        (const float*)d_in[11], (const float*)d_in[15]};
  const float* Ad[4] = {(const float*)d_in[4],  (const float*)d_in[8],
                        (const float*)d_in[12], (const float*)d_in[16]};
  const float* Bs[4] = {(const float*)d_in[5],  (const float*)d_in[9],
                        (const float*)d_in[13], (const float*)d_in[17]};

  char* p = (char*)d_ws;
  auto alloc = [&](size_t bytes) {
    char* r = p;
    p += (bytes + 255) & ~(size_t)255;
    return r;
  };
  int*   cursor = (int*)alloc(sizeof(int) * NNODES);          // counts -> cursor
  int*   indptr = (int*)alloc(sizeof(int) * (NNODES + 1));
  int*   csrc   = (int*)alloc(sizeof(int) * NTOT);
  float* alps   = (float*)alloc(sizeof(float) * NNODES * 4);
  float* alpd   = (float*)alloc(sizeof(float) * NNODES * 4);
  float* bufA   = (float*)alloc(sizeof(float) * (size_t)NNODES * 128);
  float* bufH   = (float*)alloc(sizeof(float) * (size_t)NNODES * 128);

  hipMemsetAsync(cursor, 0, sizeof(int) * NNODES, stream);
  hist_kernel   <<<(NTOT + 255) / 256, 256, 0, stream>>>(ei, cursor);
  scan_kernel   <<<1, 1024, 0, stream>>>(cursor, indptr);
  scatter_kernel<<<(NTOT + 255) / 256, 256, 0, stream>>>(ei, cursor, csrc);

  const float* cur = x;
  for (int l = 0; l < 4; ++l) {
    gemm_alpha_kernel<<<(NNODES + 31) / 32, 256, 0, stream>>>(
        cur, W[l], As[l], Ad[l], bufH, alps, alpd);
    float* o = (l == 3) ? (float*)d_out : bufA;
    agg_kernel<<<(NNODES * 64 + 255) / 256, 256, 0, stream>>>(
        bufH, alps, alpd, indptr, csrc, Bs[l], o, (l < 3) ? 1 : 0);
    cur = o;
  }
}

// Round 2
// 502.542 us; speedup vs baseline: 1.4610x; 1.4610x over previous
//
#include <hip/hip_runtime.h>
#include <math.h>

#define NNODES 50000
#define NEDGES 800000
#define NTOT   (NNODES + NEDGES)
#define NB     ((NNODES + 1023) / 1024)

// ---------------- CSR build ----------------

__global__ __launch_bounds__(256) void hist_kernel(const int* __restrict__ ei,
                                                   int* __restrict__ counts) {
  int e = blockIdx.x * 256 + threadIdx.x;
  if (e >= NTOT) return;
  int dst = (e < NEDGES) ? ei[NEDGES + e] : (e - NEDGES);
  atomicAdd(&counts[dst], 1);
}

// per-block exclusive scan of counts -> indptr (partial), block totals -> btot
__global__ __launch_bounds__(1024) void scan_blk(const int* __restrict__ counts,
                                                 int* __restrict__ indptr,
                                                 int* __restrict__ btot) {
  __shared__ int wsum[16];
  __shared__ int wpre[16];
  int t = threadIdx.x;
  int lane = t & 63, w = t >> 6;
  int i = blockIdx.x * 1024 + t;
  int v = (i < NNODES) ? counts[i] : 0;
  int x = v;
  #pragma unroll
  for (int off = 1; off < 64; off <<= 1) {
    int y = __shfl_up(x, off, 64);
    if (lane >= off) x += y;
  }
  if (lane == 63) wsum[w] = x;
  __syncthreads();
  if (t < 16) {
    int s = wsum[t];
    int xs = s;
    #pragma unroll
    for (int off = 1; off < 16; off <<= 1) {
      int y = __shfl_up(xs, off, 16);
      if (t >= off) xs += y;
    }
    wpre[t] = xs - s;
    if (t == 15) btot[blockIdx.x] = xs;
  }
  __syncthreads();
  if (i < NNODES) indptr[i] = wpre[w] + (x - v);
}

// scan the NB block totals in-place -> exclusive bases
__global__ __launch_bounds__(64) void scan_btot(int* __restrict__ btot,
                                                int* __restrict__ indptr) {
  int t = threadIdx.x;
  int v = (t < NB) ? btot[t] : 0;
  int x = v;
  #pragma unroll
  for (int off = 1; off < 64; off <<= 1) {
    int y = __shfl_up(x, off, 64);
    if (t >= off) x += y;
  }
  if (t < NB) btot[t] = x - v;
  if (t == 0) indptr[NNODES] = NTOT;
}

__global__ __launch_bounds__(256) void add_base(int* __restrict__ indptr,
                                                const int* __restrict__ bbase,
                                                int* __restrict__ cursor) {
  int i = blockIdx.x * 256 + threadIdx.x;
  if (i >= NNODES) return;
  int v = indptr[i] + bbase[i >> 10];
  indptr[i] = v;
  cursor[i] = v;
}

__global__ __launch_bounds__(256) void scatter_kernel(const int* __restrict__ ei,
                                                      int* __restrict__ cursor,
                                                      int* __restrict__ csrc) {
  int e = blockIdx.x * 256 + threadIdx.x;
  if (e >= NTOT) return;
  int src, dst;
  if (e < NEDGES) { src = ei[e]; dst = ei[NEDGES + e]; }
  else            { src = e - NEDGES; dst = src; }
  int pos = atomicAdd(&cursor[dst], 1);
  csrc[pos] = src;
}

// ---------------- GEMM h = X @ W  (+ fused alpha_src/dst = h . a) ----------------
// block 256 threads = 64 rows x 128 cols, K chunked 2x64, 8x4 micro-tile.

__global__ __launch_bounds__(256) void gemm_alpha_kernel(
    const float* __restrict__ X, const float* __restrict__ Wm,
    const float* __restrict__ a_src, const float* __restrict__ a_dst,
    float* __restrict__ H, float* __restrict__ alps, float* __restrict__ alpd) {
  __shared__ float wl[64][128];   // 32 KB
  __shared__ float xt[64][72];    // 18.4 KB (padded)
  int t = threadIdx.x;
  int r0 = blockIdx.x * 64;
  int tr = t >> 5;   // 0..7 -> rows tr*8..+7
  int tc = t & 31;   // cols tc*4..+3

  float acc[8][4];
  #pragma unroll
  for (int r = 0; r < 8; ++r)
    #pragma unroll
    for (int c = 0; c < 4; ++c) acc[r][c] = 0.f;

  for (int kc = 0; kc < 128; kc += 64) {
    __syncthreads();
    { // stage W chunk [64][128]: 2048 float4 / 256 thr = 8 each
      const float4* W4 = (const float4*)(Wm + (size_t)kc * 128);
      float4* wl4 = (float4*)wl;
      #pragma unroll
      for (int i = 0; i < 8; ++i) wl4[t + 256 * i] = W4[t + 256 * i];
    }
    { // stage X^T chunk: r = t&63, k0 = (t>>6)*16
      int r = t & 63;
      int k0 = (t >> 6) * 16;
      int row = r0 + r;
      if (row < NNODES) {
        const float4* xp = (const float4*)(X + (size_t)row * 128 + kc + k0);
        #pragma unroll
        for (int q = 0; q < 4; ++q) {
          float4 v = xp[q];
          int k = k0 + q * 4;
          xt[k + 0][r] = v.x; xt[k + 1][r] = v.y;
          xt[k + 2][r] = v.z; xt[k + 3][r] = v.w;
        }
      } else {
        #pragma unroll
        for (int q = 0; q < 16; ++q) xt[k0 + q][r] = 0.f;
      }
    }
    __syncthreads();

    #pragma unroll 8
    for (int k = 0; k < 64; ++k) {
      float4 w4 = *(const float4*)(&wl[k][tc * 4]);
      float4 x0 = *(const float4*)(&xt[k][tr * 8]);
      float4 x1 = *(const float4*)(&xt[k][tr * 8 + 4]);
      float xr[8] = {x0.x, x0.y, x0.z, x0.w, x1.x, x1.y, x1.z, x1.w};
      float wc[4] = {w4.x, w4.y, w4.z, w4.w};
      #pragma unroll
      for (int r = 0; r < 8; ++r)
        #pragma unroll
        for (int c = 0; c < 4; ++c) acc[r][c] = fmaf(xr[r], wc[c], acc[r][c]);
    }
  }

  // epilogue
  int hd  = tc >> 3;
  int cin = (tc & 7) * 4;
  float as0 = a_src[hd * 32 + cin + 0], as1 = a_src[hd * 32 + cin + 1];
  float as2 = a_src[hd * 32 + cin + 2], as3 = a_src[hd * 32 + cin + 3];
  float ad0 = a_dst[hd * 32 + cin + 0], ad1 = a_dst[hd * 32 + cin + 1];
  float ad2 = a_dst[hd * 32 + cin + 2], ad3 = a_dst[hd * 32 + cin + 3];

  #pragma unroll
  for (int r = 0; r < 8; ++r) {
    int row = r0 + tr * 8 + r;
    float4 hv = make_float4(acc[r][0], acc[r][1], acc[r][2], acc[r][3]);
    float ps = hv.x * as0 + hv.y * as1 + hv.z * as2 + hv.w * as3;
    float pd = hv.x * ad0 + hv.y * ad1 + hv.z * ad2 + hv.w * ad3;
    #pragma unroll
    for (int off = 1; off < 8; off <<= 1) {
      ps += __shfl_xor(ps, off, 64);
      pd += __shfl_xor(pd, off, 64);
    }
    if (row < NNODES) {
      *(float4*)(&H[(size_t)row * 128 + tc * 4]) = hv;
      if ((tc & 7) == 0) {
        alps[row * 4 + hd] = ps;
        alpd[row * 4 + hd] = pd;
      }
    }
  }
}

// ---------------- aggregation: one wave per dst node, chunked flash softmax ----------------

__global__ __launch_bounds__(256) void agg_kernel(
    const float* __restrict__ H, const float* __restrict__ alps,
    const float* __restrict__ alpd, const int* __restrict__ indptr,
    const int* __restrict__ csrc, const float* __restrict__ bias,
    float* __restrict__ out, int relu_flag) {
  __shared__ float p_lds[4][64 * 4];
  __shared__ int   s_lds[4][64];
  int wslot = threadIdx.x >> 6;
  int wid = (blockIdx.x * 256 + threadIdx.x) >> 6;
  if (wid >= NNODES) return;
  int lane = threadIdx.x & 63;
  int hd  = lane >> 4;
  int col = hd * 32 + (lane & 15) * 2;
  int beg = indptr[wid];
  int cnt = indptr[wid + 1] - beg;

  float4 adv = *(const float4*)(&alpd[wid * 4]);  // wave-uniform broadcast

  float m0 = -INFINITY, m1 = -INFINITY, m2 = -INFINITY, m3 = -INFINITY;
  float s0 = 0.f, s1 = 0.f, s2 = 0.f, s3 = 0.f;
  float a0 = 0.f, a1 = 0.f;

  for (int base = 0; base < cnt; base += 64) {
    int nc = min(64, cnt - base);
    // ---- phase A: per-lane edge, all 4 heads ----
    float e0 = -INFINITY, e1 = -INFINITY, e2 = -INFINITY, e3 = -INFINITY;
    if (lane < nc) {
      int src = csrc[beg + base + lane];
      s_lds[wslot][lane] = src;
      float4 av = *(const float4*)(&alps[src * 4]);
      float v0 = av.x + adv.x, v1 = av.y + adv.y;
      float v2 = av.z + adv.z, v3 = av.w + adv.w;
      e0 = (v0 > 0.f) ? v0 : 0.2f * v0;
      e1 = (v1 > 0.f) ? v1 : 0.2f * v1;
      e2 = (v2 > 0.f) ? v2 : 0.2f * v2;
      e3 = (v3 > 0.f) ? v3 : 0.2f * v3;
    }
    // chunk maxes (4 butterfly reductions)
    float c0 = e0, c1 = e1, c2 = e2, c3 = e3;
    #pragma unroll
    for (int off = 1; off < 64; off <<= 1) {
      c0 = fmaxf(c0, __shfl_xor(c0, off, 64));
      c1 = fmaxf(c1, __shfl_xor(c1, off, 64));
      c2 = fmaxf(c2, __shfl_xor(c2, off, 64));
      c3 = fmaxf(c3, __shfl_xor(c3, off, 64));
    }
    float n0 = fmaxf(m0, c0), n1 = fmaxf(m1, c1);
    float n2 = fmaxf(m2, c2), n3 = fmaxf(m3, c3);
    float sc0 = __expf(m0 - n0), sc1 = __expf(m1 - n1);
    float sc2 = __expf(m2 - n2), sc3 = __expf(m3 - n3);
    float p0 = __expf(e0 - n0), p1 = __expf(e1 - n1);
    float p2 = __expf(e2 - n2), p3 = __expf(e3 - n3);
    // chunk sums
    float q0 = p0, q1 = p1, q2 = p2, q3 = p3;
    #pragma unroll
    for (int off = 1; off < 64; off <<= 1) {
      q0 += __shfl_xor(q0, off, 64);
      q1 += __shfl_xor(q1, off, 64);
      q2 += __shfl_xor(q2, off, 64);
      q3 += __shfl_xor(q3, off, 64);
    }
    s0 = s0 * sc0 + q0; s1 = s1 * sc1 + q1;
    s2 = s2 * sc2 + q2; s3 = s3 * sc3 + q3;
    m0 = n0; m1 = n1; m2 = n2; m3 = n3;
    float sch = (hd == 0) ? sc0 : (hd == 1) ? sc1 : (hd == 2) ? sc2 : sc3;
    a0 *= sch; a1 *= sch;
    if (lane < nc) {
      *(float4*)(&p_lds[wslot][lane * 4]) = make_float4(p0, p1, p2, p3);
    }
    asm volatile("s_waitcnt lgkmcnt(0)" ::: "memory");  // wave-local LDS RAW
    // ---- phase B: independent gather-accumulate ----
    #pragma unroll 4
    for (int j = 0; j < nc; ++j) {
      int sj  = s_lds[wslot][j];
      float pj = p_lds[wslot][j * 4 + hd];
      const float2 hv = *(const float2*)(&H[(size_t)sj * 128 + col]);
      a0 = fmaf(pj, hv.x, a0);
      a1 = fmaf(pj, hv.y, a1);
    }
  }

  float sh = (hd == 0) ? s0 : (hd == 1) ? s1 : (hd == 2) ? s2 : s3;
  float inv = 1.0f / sh;
  const float2 bv = *(const float2*)(&bias[col]);
  float o0 = a0 * inv + bv.x;
  float o1 = a1 * inv + bv.y;
  if (relu_flag) { o0 = fmaxf(o0, 0.f); o1 = fmaxf(o1, 0.f); }
  *(float2*)(&out[(size_t)wid * 128 + col]) = make_float2(o0, o1);
}

// ---------------- launch ----------------

extern "C" void kernel_launch(void* const* d_in, const int* in_sizes, int n_in,
                              void* d_out, int out_size, void* d_ws, size_t ws_size,
                              hipStream_t stream) {
  const float* x  = (const float*)d_in[0];
  const int*   ei = (const int*)d_in[1];
  const float* W[4]  = {(const float*)d_in[2],  (const float*)d_in[6],
                        (const float*)d_in[10], (const float*)d_in[14]};
  const float* As[4] = {(const float*)d_in[3],  (const float*)d_in[7],
                        (const float*)d_in[11], (const float*)d_in[15]};
  const float* Ad[4] = {(const float*)d_in[4],  (const float*)d_in[8],
                        (const float*)d_in[12], (const float*)d_in[16]};
  const float* Bs[4] = {(const float*)d_in[5],  (const float*)d_in[9],
                        (const float*)d_in[13], (const float*)d_in[17]};

  char* p = (char*)d_ws;
  auto alloc = [&](size_t bytes) {
    char* r = p;
    p += (bytes + 255) & ~(size_t)255;
    return r;
  };
  int*   cursor = (int*)alloc(sizeof(int) * NNODES);
  int*   indptr = (int*)alloc(sizeof(int) * (NNODES + 1));
  int*   csrc   = (int*)alloc(sizeof(int) * NTOT);
  int*   btot   = (int*)alloc(sizeof(int) * 64);
  float* alps   = (float*)alloc(sizeof(float) * NNODES * 4);
  float* alpd   = (float*)alloc(sizeof(float) * NNODES * 4);
  float* bufA   = (float*)alloc(sizeof(float) * (size_t)NNODES * 128);
  float* bufH   = (float*)alloc(sizeof(float) * (size_t)NNODES * 128);

  hipMemsetAsync(cursor, 0, sizeof(int) * NNODES, stream);
  hist_kernel   <<<(NTOT + 255) / 256, 256, 0, stream>>>(ei, cursor);
  scan_blk      <<<NB, 1024, 0, stream>>>(cursor, indptr, btot);
  scan_btot     <<<1, 64, 0, stream>>>(btot, indptr);
  add_base      <<<(NNODES + 255) / 256, 256, 0, stream>>>(indptr, btot, cursor);
  scatter_kernel<<<(NTOT + 255) / 256, 256, 0, stream>>>(ei, cursor, csrc);

  const float* cur = x;
  for (int l = 0; l < 4; ++l) {
    gemm_alpha_kernel<<<(NNODES + 63) / 64, 256, 0, stream>>>(
        cur, W[l], As[l], Ad[l], bufH, alps, alpd);
    float* o = (l == 3) ? (float*)d_out : bufA;
    agg_kernel<<<(NNODES * 64 + 255) / 256, 256, 0, stream>>>(
        bufH, alps, alpd, indptr, csrc, Bs[l], o, (l < 3) ? 1 : 0);
    cur = o;
  }
}

// Round 3
// 465.986 us; speedup vs baseline: 1.5756x; 1.0784x over previous
//
#include <hip/hip_runtime.h>
#include <hip/hip_fp16.h>
#include <math.h>

#define NNODES 50000
#define NEDGES 800000
#define NTOT   (NNODES + NEDGES)
#define NB     ((NNODES + 1023) / 1024)

// ---------------- CSR build ----------------

__global__ __launch_bounds__(256) void hist_kernel(const int* __restrict__ ei,
                                                   int* __restrict__ counts) {
  int e = blockIdx.x * 256 + threadIdx.x;
  if (e >= NTOT) return;
  int dst = (e < NEDGES) ? ei[NEDGES + e] : (e - NEDGES);
  atomicAdd(&counts[dst], 1);
}

__global__ __launch_bounds__(1024) void scan_blk(const int* __restrict__ counts,
                                                 int* __restrict__ indptr,
                                                 int* __restrict__ btot) {
  __shared__ int wsum[16];
  __shared__ int wpre[16];
  int t = threadIdx.x;
  int lane = t & 63, w = t >> 6;
  int i = blockIdx.x * 1024 + t;
  int v = (i < NNODES) ? counts[i] : 0;
  int x = v;
  #pragma unroll
  for (int off = 1; off < 64; off <<= 1) {
    int y = __shfl_up(x, off, 64);
    if (lane >= off) x += y;
  }
  if (lane == 63) wsum[w] = x;
  __syncthreads();
  if (t < 16) {
    int s = wsum[t];
    int xs = s;
    #pragma unroll
    for (int off = 1; off < 16; off <<= 1) {
      int y = __shfl_up(xs, off, 16);
      if (t >= off) xs += y;
    }
    wpre[t] = xs - s;
    if (t == 15) btot[blockIdx.x] = xs;
  }
  __syncthreads();
  if (i < NNODES) indptr[i] = wpre[w] + (x - v);
}

__global__ __launch_bounds__(64) void scan_btot(int* __restrict__ btot,
                                                int* __restrict__ indptr) {
  int t = threadIdx.x;
  int v = (t < NB) ? btot[t] : 0;
  int x = v;
  #pragma unroll
  for (int off = 1; off < 64; off <<= 1) {
    int y = __shfl_up(x, off, 64);
    if (t >= off) x += y;
  }
  if (t < NB) btot[t] = x - v;
  if (t == 0) indptr[NNODES] = NTOT;
}

__global__ __launch_bounds__(256) void add_base(int* __restrict__ indptr,
                                                const int* __restrict__ bbase,
                                                int* __restrict__ cursor) {
  int i = blockIdx.x * 256 + threadIdx.x;
  if (i >= NNODES) return;
  int v = indptr[i] + bbase[i >> 10];
  indptr[i] = v;
  cursor[i] = v;
}

__global__ __launch_bounds__(256) void scatter_kernel(const int* __restrict__ ei,
                                                      int* __restrict__ cursor,
                                                      int* __restrict__ csrc) {
  int e = blockIdx.x * 256 + threadIdx.x;
  if (e >= NTOT) return;
  int src, dst;
  if (e < NEDGES) { src = ei[e]; dst = ei[NEDGES + e]; }
  else            { src = e - NEDGES; dst = src; }
  int pos = atomicAdd(&cursor[dst], 1);
  csrc[pos] = src;
}

// ---------------- GEMM h = X @ W  (+ fused alpha = h.a, fp16 H output) ----------------
// block 256 threads = 64 rows x 128 cols, K chunked 2x64, 8x4 micro-tile.

__global__ __launch_bounds__(256) void gemm_alpha_kernel(
    const float* __restrict__ X, const float* __restrict__ Wm,
    const float* __restrict__ a_src, const float* __restrict__ a_dst,
    __half* __restrict__ Hh, float* __restrict__ alps, float* __restrict__ alpd) {
  __shared__ float wl[64][128];   // 32 KB
  __shared__ float xt[64][72];    // 18.4 KB (padded)
  int t = threadIdx.x;
  int r0 = blockIdx.x * 64;
  int tr = t >> 5;   // 0..7 -> rows tr*8..+7
  int tc = t & 31;   // cols tc*4..+3

  float acc[8][4];
  #pragma unroll
  for (int r = 0; r < 8; ++r)
    #pragma unroll
    for (int c = 0; c < 4; ++c) acc[r][c] = 0.f;

  for (int kc = 0; kc < 128; kc += 64) {
    __syncthreads();
    {
      const float4* W4 = (const float4*)(Wm + (size_t)kc * 128);
      float4* wl4 = (float4*)wl;
      #pragma unroll
      for (int i = 0; i < 8; ++i) wl4[t + 256 * i] = W4[t + 256 * i];
    }
    {
      int r = t & 63;
      int k0 = (t >> 6) * 16;
      int row = r0 + r;
      if (row < NNODES) {
        const float4* xp = (const float4*)(X + (size_t)row * 128 + kc + k0);
        #pragma unroll
        for (int q = 0; q < 4; ++q) {
          float4 v = xp[q];
          int k = k0 + q * 4;
          xt[k + 0][r] = v.x; xt[k + 1][r] = v.y;
          xt[k + 2][r] = v.z; xt[k + 3][r] = v.w;
        }
      } else {
        #pragma unroll
        for (int q = 0; q < 16; ++q) xt[k0 + q][r] = 0.f;
      }
    }
    __syncthreads();

    #pragma unroll 8
    for (int k = 0; k < 64; ++k) {
      float4 w4 = *(const float4*)(&wl[k][tc * 4]);
      float4 x0 = *(const float4*)(&xt[k][tr * 8]);
      float4 x1 = *(const float4*)(&xt[k][tr * 8 + 4]);
      float xr[8] = {x0.x, x0.y, x0.z, x0.w, x1.x, x1.y, x1.z, x1.w};
      float wc[4] = {w4.x, w4.y, w4.z, w4.w};
      #pragma unroll
      for (int r = 0; r < 8; ++r)
        #pragma unroll
        for (int c = 0; c < 4; ++c) acc[r][c] = fmaf(xr[r], wc[c], acc[r][c]);
    }
  }

  // epilogue
  int hd  = tc >> 3;
  int cin = (tc & 7) * 4;
  float as0 = a_src[hd * 32 + cin + 0], as1 = a_src[hd * 32 + cin + 1];
  float as2 = a_src[hd * 32 + cin + 2], as3 = a_src[hd * 32 + cin + 3];
  float ad0 = a_dst[hd * 32 + cin + 0], ad1 = a_dst[hd * 32 + cin + 1];
  float ad2 = a_dst[hd * 32 + cin + 2], ad3 = a_dst[hd * 32 + cin + 3];

  #pragma unroll
  for (int r = 0; r < 8; ++r) {
    int row = r0 + tr * 8 + r;
    float ps = acc[r][0] * as0 + acc[r][1] * as1 + acc[r][2] * as2 + acc[r][3] * as3;
    float pd = acc[r][0] * ad0 + acc[r][1] * ad1 + acc[r][2] * ad2 + acc[r][3] * ad3;
    #pragma unroll
    for (int off = 1; off < 8; off <<= 1) {
      ps += __shfl_xor(ps, off, 64);
      pd += __shfl_xor(pd, off, 64);
    }
    if (row < NNODES) {
      __half2 h01 = __floats2half2_rn(acc[r][0], acc[r][1]);
      __half2 h23 = __floats2half2_rn(acc[r][2], acc[r][3]);
      __half2* hp = (__half2*)(&Hh[(size_t)row * 128 + tc * 4]);
      hp[0] = h01;
      hp[1] = h23;
      if ((tc & 7) == 0) {
        alps[row * 4 + hd] = ps;
        alpd[row * 4 + hd] = pd;
      }
    }
  }
}

// ---------------- aggregation: one wave per dst node, chunked flash softmax ----------------

__global__ __launch_bounds__(256) void agg_kernel(
    const __half* __restrict__ Hh, const float* __restrict__ alps,
    const float* __restrict__ alpd, const int* __restrict__ indptr,
    const int* __restrict__ csrc, const float* __restrict__ bias,
    float* __restrict__ out, int relu_flag) {
  __shared__ float p_lds[4][64 * 4];
  __shared__ int   s_lds[4][64];
  int wslot = threadIdx.x >> 6;
  int wid = (blockIdx.x * 256 + threadIdx.x) >> 6;
  if (wid >= NNODES) return;
  int lane = threadIdx.x & 63;
  int hd  = lane >> 4;
  int col = hd * 32 + (lane & 15) * 2;
  int beg = indptr[wid];
  int cnt = indptr[wid + 1] - beg;

  float4 adv = *(const float4*)(&alpd[wid * 4]);

  float m0 = -INFINITY, m1 = -INFINITY, m2 = -INFINITY, m3 = -INFINITY;
  float s0 = 0.f, s1 = 0.f, s2 = 0.f, s3 = 0.f;
  float a0 = 0.f, a1 = 0.f;

  for (int base = 0; base < cnt; base += 64) {
    int nc = min(64, cnt - base);
    float e0 = -INFINITY, e1 = -INFINITY, e2 = -INFINITY, e3 = -INFINITY;
    if (lane < nc) {
      int src = csrc[beg + base + lane];
      s_lds[wslot][lane] = src;
      float4 av = *(const float4*)(&alps[src * 4]);
      float v0 = av.x + adv.x, v1 = av.y + adv.y;
      float v2 = av.z + adv.z, v3 = av.w + adv.w;
      e0 = (v0 > 0.f) ? v0 : 0.2f * v0;
      e1 = (v1 > 0.f) ? v1 : 0.2f * v1;
      e2 = (v2 > 0.f) ? v2 : 0.2f * v2;
      e3 = (v3 > 0.f) ? v3 : 0.2f * v3;
    }
    float c0 = e0, c1 = e1, c2 = e2, c3 = e3;
    #pragma unroll
    for (int off = 1; off < 64; off <<= 1) {
      c0 = fmaxf(c0, __shfl_xor(c0, off, 64));
      c1 = fmaxf(c1, __shfl_xor(c1, off, 64));
      c2 = fmaxf(c2, __shfl_xor(c2, off, 64));
      c3 = fmaxf(c3, __shfl_xor(c3, off, 64));
    }
    float n0 = fmaxf(m0, c0), n1 = fmaxf(m1, c1);
    float n2 = fmaxf(m2, c2), n3 = fmaxf(m3, c3);
    float sc0 = __expf(m0 - n0), sc1 = __expf(m1 - n1);
    float sc2 = __expf(m2 - n2), sc3 = __expf(m3 - n3);
    float p0 = __expf(e0 - n0), p1 = __expf(e1 - n1);
    float p2 = __expf(e2 - n2), p3 = __expf(e3 - n3);
    float q0 = p0, q1 = p1, q2 = p2, q3 = p3;
    #pragma unroll
    for (int off = 1; off < 64; off <<= 1) {
      q0 += __shfl_xor(q0, off, 64);
      q1 += __shfl_xor(q1, off, 64);
      q2 += __shfl_xor(q2, off, 64);
      q3 += __shfl_xor(q3, off, 64);
    }
    s0 = s0 * sc0 + q0; s1 = s1 * sc1 + q1;
    s2 = s2 * sc2 + q2; s3 = s3 * sc3 + q3;
    m0 = n0; m1 = n1; m2 = n2; m3 = n3;
    float sch = (hd == 0) ? sc0 : (hd == 1) ? sc1 : (hd == 2) ? sc2 : sc3;
    a0 *= sch; a1 *= sch;
    if (lane < nc) {
      *(float4*)(&p_lds[wslot][lane * 4]) = make_float4(p0, p1, p2, p3);
    }
    asm volatile("s_waitcnt lgkmcnt(0)" ::: "memory");
    #pragma unroll 8
    for (int j = 0; j < nc; ++j) {
      int sj  = s_lds[wslot][j];
      float pj = p_lds[wslot][j * 4 + hd];
      const __half2 hv2 = *(const __half2*)(&Hh[(size_t)sj * 128 + col]);
      float2 hv = __half22float2(hv2);
      a0 = fmaf(pj, hv.x, a0);
      a1 = fmaf(pj, hv.y, a1);
    }
  }

  float sh = (hd == 0) ? s0 : (hd == 1) ? s1 : (hd == 2) ? s2 : s3;
  float inv = 1.0f / sh;
  const float2 bv = *(const float2*)(&bias[col]);
  float o0 = a0 * inv + bv.x;
  float o1 = a1 * inv + bv.y;
  if (relu_flag) { o0 = fmaxf(o0, 0.f); o1 = fmaxf(o1, 0.f); }
  *(float2*)(&out[(size_t)wid * 128 + col]) = make_float2(o0, o1);
}

// ---------------- launch ----------------

extern "C" void kernel_launch(void* const* d_in, const int* in_sizes, int n_in,
                              void* d_out, int out_size, void* d_ws, size_t ws_size,
                              hipStream_t stream) {
  const float* x  = (const float*)d_in[0];
  const int*   ei = (const int*)d_in[1];
  const float* W[4]  = {(const float*)d_in[2],  (const float*)d_in[6],
                        (const float*)d_in[10], (const float*)d_in[14]};
  const float* As[4] = {(const float*)d_in[3],  (const float*)d_in[7],
                        (const float*)d_in[11], (const float*)d_in[15]};
  const float* Ad[4] = {(const float*)d_in[4],  (const float*)d_in[8],
                        (const float*)d_in[12], (const float*)d_in[16]};
  const float* Bs[4] = {(const float*)d_in[5],  (const float*)d_in[9],
                        (const float*)d_in[13], (const float*)d_in[17]};

  char* p = (char*)d_ws;
  auto alloc = [&](size_t bytes) {
    char* r = p;
    p += (bytes + 255) & ~(size_t)255;
    return r;
  };
  int*    cursor = (int*)alloc(sizeof(int) * NNODES);
  int*    indptr = (int*)alloc(sizeof(int) * (NNODES + 1));
  int*    csrc   = (int*)alloc(sizeof(int) * NTOT);
  int*    btot   = (int*)alloc(sizeof(int) * 64);
  float*  alps   = (float*)alloc(sizeof(float) * NNODES * 4);
  float*  alpd   = (float*)alloc(sizeof(float) * NNODES * 4);
  float*  bufA   = (float*)alloc(sizeof(float) * (size_t)NNODES * 128);
  __half* Hh     = (__half*)alloc(sizeof(__half) * (size_t)NNODES * 128);

  hipMemsetAsync(cursor, 0, sizeof(int) * NNODES, stream);
  hist_kernel   <<<(NTOT + 255) / 256, 256, 0, stream>>>(ei, cursor);
  scan_blk      <<<NB, 1024, 0, stream>>>(cursor, indptr, btot);
  scan_btot     <<<1, 64, 0, stream>>>(btot, indptr);
  add_base      <<<(NNODES + 255) / 256, 256, 0, stream>>>(indptr, btot, cursor);
  scatter_kernel<<<(NTOT + 255) / 256, 256, 0, stream>>>(ei, cursor, csrc);

  const float* cur = x;
  for (int l = 0; l < 4; ++l) {
    gemm_alpha_kernel<<<(NNODES + 63) / 64, 256, 0, stream>>>(
        cur, W[l], As[l], Ad[l], Hh, alps, alpd);
    float* o = (l == 3) ? (float*)d_out : bufA;
    agg_kernel<<<(NNODES * 64 + 255) / 256, 256, 0, stream>>>(
        Hh, alps, alpd, indptr, csrc, Bs[l], o, (l < 3) ? 1 : 0);
    cur = o;
  }
}

// Round 4
// 430.544 us; speedup vs baseline: 1.7053x; 1.0823x over previous
//
#include <hip/hip_runtime.h>
#include <hip/hip_fp16.h>
#include <math.h>

#define NNODES 50000
#define NEDGES 800000
#define NTOT   (NNODES + NEDGES)
#define NB     ((NNODES + 1023) / 1024)
#define GROWS  96

typedef _Float16 half8 __attribute__((ext_vector_type(8)));
typedef _Float16 half4 __attribute__((ext_vector_type(4)));
typedef float    f32x4 __attribute__((ext_vector_type(4)));

// ---------------- CSR build ----------------

__global__ __launch_bounds__(256) void hist_kernel(const int* __restrict__ ei,
                                                   int* __restrict__ counts) {
  int e = blockIdx.x * 256 + threadIdx.x;
  if (e >= NTOT) return;
  int dst = (e < NEDGES) ? ei[NEDGES + e] : (e - NEDGES);
  atomicAdd(&counts[dst], 1);
}

__global__ __launch_bounds__(1024) void scan_blk(const int* __restrict__ counts,
                                                 int* __restrict__ indptr,
                                                 int* __restrict__ btot) {
  __shared__ int wsum[16];
  __shared__ int wpre[16];
  int t = threadIdx.x;
  int lane = t & 63, w = t >> 6;
  int i = blockIdx.x * 1024 + t;
  int v = (i < NNODES) ? counts[i] : 0;
  int x = v;
  #pragma unroll
  for (int off = 1; off < 64; off <<= 1) {
    int y = __shfl_up(x, off, 64);
    if (lane >= off) x += y;
  }
  if (lane == 63) wsum[w] = x;
  __syncthreads();
  if (t < 16) {
    int s = wsum[t];
    int xs = s;
    #pragma unroll
    for (int off = 1; off < 16; off <<= 1) {
      int y = __shfl_up(xs, off, 16);
      if (t >= off) xs += y;
    }
    wpre[t] = xs - s;
    if (t == 15) btot[blockIdx.x] = xs;
  }
  __syncthreads();
  if (i < NNODES) indptr[i] = wpre[w] + (x - v);
}

__global__ __launch_bounds__(64) void scan_btot(int* __restrict__ btot,
                                                int* __restrict__ indptr) {
  int t = threadIdx.x;
  int v = (t < NB) ? btot[t] : 0;
  int x = v;
  #pragma unroll
  for (int off = 1; off < 64; off <<= 1) {
    int y = __shfl_up(x, off, 64);
    if (t >= off) x += y;
  }
  if (t < NB) btot[t] = x - v;
  if (t == 0) indptr[NNODES] = NTOT;
}

__global__ __launch_bounds__(256) void add_base(int* __restrict__ indptr,
                                                const int* __restrict__ bbase,
                                                int* __restrict__ cursor) {
  int i = blockIdx.x * 256 + threadIdx.x;
  if (i >= NNODES) return;
  int v = indptr[i] + bbase[i >> 10];
  indptr[i] = v;
  cursor[i] = v;
}

__global__ __launch_bounds__(256) void scatter_kernel(const int* __restrict__ ei,
                                                      int* __restrict__ cursor,
                                                      int* __restrict__ csrc) {
  int e = blockIdx.x * 256 + threadIdx.x;
  if (e >= NTOT) return;
  int src, dst;
  if (e < NEDGES) { src = ei[e]; dst = ei[NEDGES + e]; }
  else            { src = e - NEDGES; dst = src; }
  int pos = atomicAdd(&cursor[dst], 1);
  csrc[pos] = src;
}

// ---------------- W prep: fp32 W[k][n] -> transposed fp16 hi/lo Wt[n][k] ----------------

__global__ __launch_bounds__(256) void wprep_kernel(const float* __restrict__ W,
                                                    _Float16* __restrict__ hi,
                                                    _Float16* __restrict__ lo) {
  int o = blockIdx.x * 256 + threadIdx.x;   // 16384 = 128x128
  int n = o >> 7, k = o & 127;
  float v = W[k * 128 + n];
  _Float16 h = (_Float16)v;
  hi[o] = h;
  lo[o] = (_Float16)(v - (float)h);
}

// ---------------- GEMM via f16 MFMA, hi/lo compensated ----------------
// block 384 thr = 6 waves x 16 rows = 96 rows; all 128 cols per wave (8 tiles).
// D[i=h-col][j=h-row]: A = Wt (16x32 of W^T), B = X rows.

__global__ __launch_bounds__(384) void gemm_mfma_kernel(
    const float* __restrict__ X, const _Float16* __restrict__ Wthi,
    const _Float16* __restrict__ Wtlo,
    const float* __restrict__ a_src, const float* __restrict__ a_dst,
    _Float16* __restrict__ Hh, float* __restrict__ alps, float* __restrict__ alpd) {
  __shared__ _Float16 whi[128 * 136];   // padded stride 136 halves (272 B, 16B-mult)
  __shared__ _Float16 wlo[128 * 136];
  int t = threadIdx.x;

  for (int i = t; i < 2048; i += 384) {   // 2048 chunks of 8 halves
    int n = i >> 4, koff = (i & 15) * 8;
    *(half8*)&whi[n * 136 + koff] = *(const half8*)&Wthi[n * 128 + koff];
    *(half8*)&wlo[n * 136 + koff] = *(const half8*)&Wtlo[n * 128 + koff];
  }
  __syncthreads();

  int wave = t >> 6, lane = t & 63;
  int row  = blockIdx.x * GROWS + wave * 16 + (lane & 15);
  int kg   = (lane >> 4) * 8;
  bool valid = row < NNODES;

  f32x4 acc[8];
  #pragma unroll
  for (int tl = 0; tl < 8; ++tl) acc[tl] = (f32x4){0.f, 0.f, 0.f, 0.f};

  #pragma unroll
  for (int kt = 0; kt < 4; ++kt) {
    int k0 = kt * 32 + kg;
    half8 bh, bl;
    if (valid) {
      const float* xp = X + (size_t)row * 128 + k0;
      float4 f0 = *(const float4*)xp;
      float4 f1 = *(const float4*)(xp + 4);
      float fv[8] = {f0.x, f0.y, f0.z, f0.w, f1.x, f1.y, f1.z, f1.w};
      #pragma unroll
      for (int j = 0; j < 8; ++j) {
        _Float16 h = (_Float16)fv[j];
        bh[j] = h;
        bl[j] = (_Float16)(fv[j] - (float)h);
      }
    } else {
      #pragma unroll
      for (int j = 0; j < 8; ++j) { bh[j] = (_Float16)0.f; bl[j] = (_Float16)0.f; }
    }
    #pragma unroll
    for (int tl = 0; tl < 8; ++tl) {
      int aoff = (tl * 16 + (lane & 15)) * 136 + k0;
      half8 ah = *(const half8*)&whi[aoff];
      half8 al = *(const half8*)&wlo[aoff];
      acc[tl] = __builtin_amdgcn_mfma_f32_16x16x32_f16(ah, bh, acc[tl], 0, 0, 0);
      acc[tl] = __builtin_amdgcn_mfma_f32_16x16x32_f16(ah, bl, acc[tl], 0, 0, 0);
      acc[tl] = __builtin_amdgcn_mfma_f32_16x16x32_f16(al, bh, acc[tl], 0, 0, 0);
    }
  }

  // epilogue: Hh fp16 write + alpha dot-products (fp32-exact h)
  int cg = (lane >> 4) * 4;
  float ps[4] = {0.f, 0.f, 0.f, 0.f}, pd[4] = {0.f, 0.f, 0.f, 0.f};
  #pragma unroll
  for (int tl = 0; tl < 8; ++tl) {
    int col0 = tl * 16 + cg;
    float4 as4 = *(const float4*)&a_src[col0];
    float4 ad4 = *(const float4*)&a_dst[col0];
    int hd = tl >> 1;
    ps[hd] += acc[tl][0] * as4.x + acc[tl][1] * as4.y + acc[tl][2] * as4.z + acc[tl][3] * as4.w;
    pd[hd] += acc[tl][0] * ad4.x + acc[tl][1] * ad4.y + acc[tl][2] * ad4.z + acc[tl][3] * ad4.w;
    if (valid) {
      half4 hv;
      hv[0] = (_Float16)acc[tl][0]; hv[1] = (_Float16)acc[tl][1];
      hv[2] = (_Float16)acc[tl][2]; hv[3] = (_Float16)acc[tl][3];
      *(half4*)&Hh[(size_t)row * 128 + col0] = hv;
    }
  }
  #pragma unroll
  for (int hd = 0; hd < 4; ++hd) {
    ps[hd] += __shfl_xor(ps[hd], 16, 64);
    ps[hd] += __shfl_xor(ps[hd], 32, 64);
    pd[hd] += __shfl_xor(pd[hd], 16, 64);
    pd[hd] += __shfl_xor(pd[hd], 32, 64);
  }
  if (valid && lane < 16) {
    *(f32x4*)&alps[row * 4] = (f32x4){ps[0], ps[1], ps[2], ps[3]};
    *(f32x4*)&alpd[row * 4] = (f32x4){pd[0], pd[1], pd[2], pd[3]};
  }
}

// ---------------- aggregation: one wave per dst node, chunked flash softmax ----------------

__global__ __launch_bounds__(256) void agg_kernel(
    const __half* __restrict__ Hh, const float* __restrict__ alps,
    const float* __restrict__ alpd, const int* __restrict__ indptr,
    const int* __restrict__ csrc, const float* __restrict__ bias,
    float* __restrict__ out, int relu_flag) {
  __shared__ float p_lds[4][64 * 4];
  __shared__ int   s_lds[4][64];
  int wslot = threadIdx.x >> 6;
  int wid = (blockIdx.x * 256 + threadIdx.x) >> 6;
  if (wid >= NNODES) return;
  int lane = threadIdx.x & 63;
  int hd  = lane >> 4;
  int col = hd * 32 + (lane & 15) * 2;
  int beg = indptr[wid];
  int cnt = indptr[wid + 1] - beg;

  float4 adv = *(const float4*)(&alpd[wid * 4]);

  float m0 = -INFINITY, m1 = -INFINITY, m2 = -INFINITY, m3 = -INFINITY;
  float s0 = 0.f, s1 = 0.f, s2 = 0.f, s3 = 0.f;
  float a0 = 0.f, a1 = 0.f;

  for (int base = 0; base < cnt; base += 64) {
    int nc = min(64, cnt - base);
    float e0 = -INFINITY, e1 = -INFINITY, e2 = -INFINITY, e3 = -INFINITY;
    if (lane < nc) {
      int src = csrc[beg + base + lane];
      s_lds[wslot][lane] = src;
      float4 av = *(const float4*)(&alps[src * 4]);
      float v0 = av.x + adv.x, v1 = av.y + adv.y;
      float v2 = av.z + adv.z, v3 = av.w + adv.w;
      e0 = (v0 > 0.f) ? v0 : 0.2f * v0;
      e1 = (v1 > 0.f) ? v1 : 0.2f * v1;
      e2 = (v2 > 0.f) ? v2 : 0.2f * v2;
      e3 = (v3 > 0.f) ? v3 : 0.2f * v3;
    }
    float c0 = e0, c1 = e1, c2 = e2, c3 = e3;
    #pragma unroll
    for (int off = 1; off < 64; off <<= 1) {
      c0 = fmaxf(c0, __shfl_xor(c0, off, 64));
      c1 = fmaxf(c1, __shfl_xor(c1, off, 64));
      c2 = fmaxf(c2, __shfl_xor(c2, off, 64));
      c3 = fmaxf(c3, __shfl_xor(c3, off, 64));
    }
    float n0 = fmaxf(m0, c0), n1 = fmaxf(m1, c1);
    float n2 = fmaxf(m2, c2), n3 = fmaxf(m3, c3);
    float sc0 = __expf(m0 - n0), sc1 = __expf(m1 - n1);
    float sc2 = __expf(m2 - n2), sc3 = __expf(m3 - n3);
    float p0 = __expf(e0 - n0), p1 = __expf(e1 - n1);
    float p2 = __expf(e2 - n2), p3 = __expf(e3 - n3);
    float q0 = p0, q1 = p1, q2 = p2, q3 = p3;
    #pragma unroll
    for (int off = 1; off < 64; off <<= 1) {
      q0 += __shfl_xor(q0, off, 64);
      q1 += __shfl_xor(q1, off, 64);
      q2 += __shfl_xor(q2, off, 64);
      q3 += __shfl_xor(q3, off, 64);
    }
    s0 = s0 * sc0 + q0; s1 = s1 * sc1 + q1;
    s2 = s2 * sc2 + q2; s3 = s3 * sc3 + q3;
    m0 = n0; m1 = n1; m2 = n2; m3 = n3;
    float sch = (hd == 0) ? sc0 : (hd == 1) ? sc1 : (hd == 2) ? sc2 : sc3;
    a0 *= sch; a1 *= sch;
    if (lane < nc) {
      *(float4*)(&p_lds[wslot][lane * 4]) = make_float4(p0, p1, p2, p3);
    }
    asm volatile("s_waitcnt lgkmcnt(0)" ::: "memory");
    #pragma unroll 8
    for (int j = 0; j < nc; ++j) {
      int sj  = s_lds[wslot][j];
      float pj = p_lds[wslot][j * 4 + hd];
      const __half2 hv2 = *(const __half2*)(&Hh[(size_t)sj * 128 + col]);
      float2 hv = __half22float2(hv2);
      a0 = fmaf(pj, hv.x, a0);
      a1 = fmaf(pj, hv.y, a1);
    }
  }

  float sh = (hd == 0) ? s0 : (hd == 1) ? s1 : (hd == 2) ? s2 : s3;
  float inv = 1.0f / sh;
  const float2 bv = *(const float2*)(&bias[col]);
  float o0 = a0 * inv + bv.x;
  float o1 = a1 * inv + bv.y;
  if (relu_flag) { o0 = fmaxf(o0, 0.f); o1 = fmaxf(o1, 0.f); }
  *(float2*)(&out[(size_t)wid * 128 + col]) = make_float2(o0, o1);
}

// ---------------- launch ----------------

extern "C" void kernel_launch(void* const* d_in, const int* in_sizes, int n_in,
                              void* d_out, int out_size, void* d_ws, size_t ws_size,
                              hipStream_t stream) {
  const float* x  = (const float*)d_in[0];
  const int*   ei = (const int*)d_in[1];
  const float* W[4]  = {(const float*)d_in[2],  (const float*)d_in[6],
                        (const float*)d_in[10], (const float*)d_in[14]};
  const float* As[4] = {(const float*)d_in[3],  (const float*)d_in[7],
                        (const float*)d_in[11], (const float*)d_in[15]};
  const float* Ad[4] = {(const float*)d_in[4],  (const float*)d_in[8],
                        (const float*)d_in[12], (const float*)d_in[16]};
  const float* Bs[4] = {(const float*)d_in[5],  (const float*)d_in[9],
                        (const float*)d_in[13], (const float*)d_in[17]};

  char* p = (char*)d_ws;
  auto alloc = [&](size_t bytes) {
    char* r = p;
    p += (bytes + 255) & ~(size_t)255;
    return r;
  };
  int*      cursor = (int*)alloc(sizeof(int) * NNODES);
  int*      indptr = (int*)alloc(sizeof(int) * (NNODES + 1));
  int*      csrc   = (int*)alloc(sizeof(int) * NTOT);
  int*      btot   = (int*)alloc(sizeof(int) * 64);
  float*    alps   = (float*)alloc(sizeof(float) * NNODES * 4);
  float*    alpd   = (float*)alloc(sizeof(float) * NNODES * 4);
  float*    bufA   = (float*)alloc(sizeof(float) * (size_t)NNODES * 128);
  _Float16* Hh     = (_Float16*)alloc(sizeof(_Float16) * (size_t)NNODES * 128);
  _Float16* Wthi[4], *Wtlo[4];
  for (int l = 0; l < 4; ++l) {
    Wthi[l] = (_Float16*)alloc(sizeof(_Float16) * 128 * 128);
    Wtlo[l] = (_Float16*)alloc(sizeof(_Float16) * 128 * 128);
  }

  hipMemsetAsync(cursor, 0, sizeof(int) * NNODES, stream);
  hist_kernel   <<<(NTOT + 255) / 256, 256, 0, stream>>>(ei, cursor);
  scan_blk      <<<NB, 1024, 0, stream>>>(cursor, indptr, btot);
  scan_btot     <<<1, 64, 0, stream>>>(btot, indptr);
  add_base      <<<(NNODES + 255) / 256, 256, 0, stream>>>(indptr, btot, cursor);
  scatter_kernel<<<(NTOT + 255) / 256, 256, 0, stream>>>(ei, cursor, csrc);
  for (int l = 0; l < 4; ++l)
    wprep_kernel<<<64, 256, 0, stream>>>(W[l], Wthi[l], Wtlo[l]);

  const float* cur = x;
  for (int l = 0; l < 4; ++l) {
    gemm_mfma_kernel<<<(NNODES + GROWS - 1) / GROWS, 384, 0, stream>>>(
        cur, Wthi[l], Wtlo[l], As[l], Ad[l], Hh, alps, alpd);
    float* o = (l == 3) ? (float*)d_out : bufA;
    agg_kernel<<<(NNODES * 64 + 255) / 256, 256, 0, stream>>>(
        (const __half*)Hh, alps, alpd, indptr, csrc, Bs[l], o, (l < 3) ? 1 : 0);
    cur = o;
  }
}